// Round 7
// baseline (1008.296 us; speedup 1.0000x reference)
//
#include <hip/hip_runtime.h>
#include <hip/hip_bf16.h>

#define N_NODES 100000
#define N_EDGES 1600000
#define IN_DIM_ 256
#define HID_ 256
#define OUT_ 64
#define KSTEPS 10

typedef __attribute__((ext_vector_type(4))) float f32x4;
typedef __attribute__((ext_vector_type(8))) __bf16 bf16x8;
typedef __attribute__((ext_vector_type(8))) unsigned short u16x8;

static __device__ __forceinline__ unsigned short f2bf(float f) {
    union { float f; unsigned int u; } v; v.f = f;
    unsigned int u = v.u;
    unsigned int r = u + 0x7FFFu + ((u >> 16) & 1u);  // RNE
    return (unsigned short)(r >> 16);
}
static __device__ __forceinline__ float bflo(unsigned int v) {
    return __uint_as_float(v << 16);
}
static __device__ __forceinline__ float bfhi(unsigned int v) {
    return __uint_as_float(v & 0xFFFF0000u);
}

// ---------------- small setup kernels ----------------

__global__ void gamma_kernel(const float* __restrict__ alpha, float* __restrict__ gamma) {
    if (threadIdx.x == 0) {
        float m = alpha[0];
        for (int i = 1; i <= KSTEPS; ++i) m = fmaxf(m, alpha[i]);
        float e[KSTEPS + 1];
        float s = 0.f;
        for (int i = 0; i <= KSTEPS; ++i) { e[i] = expf(alpha[i] - m); s += e[i]; }
        float inv = 1.f / s;
        for (int i = 0; i <= KSTEPS; ++i) gamma[i] = e[i] * inv;
    }
}

__global__ void deg_kernel(const int* __restrict__ row, int* __restrict__ deg, int E) {
    int e = blockIdx.x * 256 + threadIdx.x;
    if (e < E) atomicAdd(&deg[row[e]], 1);
}

__global__ void dis_kernel(const int* __restrict__ deg, float* __restrict__ dis, int n) {
    int i = blockIdx.x * 256 + threadIdx.x;
    if (i < n) {
        int d = deg[i];
        dis[i] = d > 0 ? rsqrtf((float)d) : 0.f;
    }
}

// transpose+cast weights once: wT[n][k] = bf16(W[k][n])
__global__ void wcast_kernel(const float* __restrict__ W, unsigned short* __restrict__ wT,
                             int K, int N) {
    int k = blockIdx.x * 256 + threadIdx.x;
    int n = blockIdx.y;
    if (k < K) wT[(size_t)n * K + k] = f2bf(W[(size_t)k * N + n]);
}

// ---------------- hierarchical scan ----------------

__global__ __launch_bounds__(256) void scan_sum_kernel(const int* __restrict__ deg,
                                                       int* __restrict__ bsum, int n) {
    __shared__ int s[256];
    int t = threadIdx.x;
    int i = blockIdx.x * 256 + t;
    s[t] = (i < n) ? deg[i] : 0;
    __syncthreads();
    for (int st = 128; st > 0; st >>= 1) {
        if (t < st) s[t] += s[t + st];
        __syncthreads();
    }
    if (t == 0) bsum[blockIdx.x] = s[0];
}

__global__ __launch_bounds__(512) void scan_block_kernel(int* __restrict__ bsum,
                                                         int* __restrict__ off,
                                                         int nblk, int n) {
    __shared__ int s[512];
    int t = threadIdx.x;
    int v = (t < nblk) ? bsum[t] : 0;
    s[t] = v;
    __syncthreads();
    for (int st = 1; st < 512; st <<= 1) {
        int a = (t >= st) ? s[t - st] : 0;
        __syncthreads();
        s[t] += a;
        __syncthreads();
    }
    if (t < nblk) bsum[t] = s[t] - v;  // exclusive
    if (t == 511) off[n] = s[511];     // total = E
}

__global__ __launch_bounds__(256) void scan_final_kernel(const int* __restrict__ deg,
                                                         const int* __restrict__ bsum,
                                                         int* __restrict__ off, int n) {
    __shared__ int s[256];
    int t = threadIdx.x;
    int i = blockIdx.x * 256 + t;
    int v = (i < n) ? deg[i] : 0;
    s[t] = v;
    __syncthreads();
    for (int st = 1; st < 256; st <<= 1) {
        int a = (t >= st) ? s[t - st] : 0;
        __syncthreads();
        s[t] += a;
        __syncthreads();
    }
    if (i < n) off[i] = bsum[blockIdx.x] + s[t] - v;
}

__global__ void csr_scatter_kernel(const int* __restrict__ row, const int* __restrict__ col,
                                   const float* __restrict__ dis, const int* __restrict__ off,
                                   int* __restrict__ cursor, long long* __restrict__ ecsr, int E) {
    int e = blockIdx.x * 256 + threadIdx.x;
    if (e < E) {
        int r = row[e], c = col[e];
        float w = dis[r] * dis[c];
        int pos = atomicAdd(&cursor[r], 1);
        long long packed = (long long)(unsigned int)c |
                           ((long long)(unsigned int)__float_as_int(w) << 32);
        // nt: random 8B scatter, used once per pull step from L3 — keep out of L2
        __builtin_nontemporal_store(packed, &ecsr[(size_t)off[r] + pos]);
    }
}

// ---------------- MLP ----------------
// GEMM1 single-pass: block computes 64 rows x 256 cols. x fetched exactly once.
__global__ __launch_bounds__(256) void gemm1_kernel(const float* __restrict__ x,
                                                    const unsigned short* __restrict__ w1T,
                                                    const float* __restrict__ b1,
                                                    unsigned short* __restrict__ h1, int M) {
    __shared__ unsigned short As[64][40];
    __shared__ unsigned short Bs[256][40];

    const int tid = threadIdx.x;
    const int lane = tid & 63;
    const int w = tid >> 6;
    const int wr = w >> 1, wc = w & 1;          // wave tile: rows wr*32, cols wc*128
    const int row0 = blockIdx.x * 64;

    const int am = tid >> 2;
    const int ak = (tid & 3) * 8;

    f32x4 acc[2][8] = {};

    for (int kk = 0; kk < 256; kk += 32) {
        {
            int gr = row0 + am;
            u16x8 av;
            if (gr < M) {
                const float* p = x + (size_t)gr * IN_DIM_ + kk + ak;
                #pragma unroll
                for (int j = 0; j < 8; ++j) av[j] = f2bf(p[j]);
            } else {
                #pragma unroll
                for (int j = 0; j < 8; ++j) av[j] = 0;
            }
            *(u16x8*)&As[am][ak] = av;
        }
        {
            const unsigned short* p = w1T + (size_t)tid * 256 + kk;
            *(u16x8*)&Bs[tid][0]  = *(const u16x8*)&p[0];
            *(u16x8*)&Bs[tid][8]  = *(const u16x8*)&p[8];
            *(u16x8*)&Bs[tid][16] = *(const u16x8*)&p[16];
            *(u16x8*)&Bs[tid][24] = *(const u16x8*)&p[24];
        }
        __syncthreads();

        const int fr = lane & 15;
        const int ko = (lane >> 4) * 8;
        bf16x8 a[2];
        #pragma unroll
        for (int mi = 0; mi < 2; ++mi) a[mi] = *(const bf16x8*)&As[wr * 32 + mi * 16 + fr][ko];
        #pragma unroll
        for (int ni = 0; ni < 8; ++ni) {
            bf16x8 b = *(const bf16x8*)&Bs[wc * 128 + ni * 16 + fr][ko];
            #pragma unroll
            for (int mi = 0; mi < 2; ++mi)
                acc[mi][ni] = __builtin_amdgcn_mfma_f32_16x16x32_bf16(a[mi], b, acc[mi][ni], 0, 0, 0);
        }
        __syncthreads();
    }

    const int fr = lane & 15;
    const int rg = (lane >> 4) * 4;
    #pragma unroll
    for (int mi = 0; mi < 2; ++mi) {
        #pragma unroll
        for (int r = 0; r < 4; ++r) {
            int gm = row0 + wr * 32 + mi * 16 + rg + r;
            if (gm < M) {
                #pragma unroll
                for (int ni = 0; ni < 8; ++ni) {
                    int gn = wc * 128 + ni * 16 + fr;
                    float v = acc[mi][ni][r] + b1[gn];
                    v = fmaxf(v, 0.f);
                    h1[(size_t)gm * HID_ + gn] = f2bf(v);
                }
            }
        }
    }
}

// GEMM2: h = h1 @ W2 + b2 -> h bf16 [M,64]; out = gamma0*h (f32 pre-rounding)
__global__ __launch_bounds__(256) void gemm2_kernel(const unsigned short* __restrict__ h1,
                                                    const unsigned short* __restrict__ w2T,
                                                    const float* __restrict__ b2,
                                                    const float* __restrict__ gamma,
                                                    unsigned short* __restrict__ h,
                                                    float* __restrict__ out, int M) {
    __shared__ unsigned short As[64][40];
    __shared__ unsigned short Bs[64][40];

    const int tid = threadIdx.x;
    const int lane = tid & 63;
    const int w = tid >> 6;
    const int wr = w >> 1, wc = w & 1;
    const int row0 = blockIdx.x * 64;

    const int am = tid >> 2;
    const int ak = (tid & 3) * 8;

    f32x4 acc[2][2] = {};

    for (int kk = 0; kk < 256; kk += 32) {
        {
            int gr = row0 + am;
            if (gr < M) {
                *(u16x8*)&As[am][ak] = *(const u16x8*)&h1[(size_t)gr * HID_ + kk + ak];
            } else {
                u16x8 z = {};
                *(u16x8*)&As[am][ak] = z;
            }
        }
        if (tid < 128) {
            int n = tid >> 1, hf = (tid & 1) * 16;
            const unsigned short* p = &w2T[(size_t)n * 256 + kk + hf];
            *(u16x8*)&Bs[n][hf]     = *(const u16x8*)&p[0];
            *(u16x8*)&Bs[n][hf + 8] = *(const u16x8*)&p[8];
        }
        __syncthreads();

        const int fr = lane & 15;
        const int ko = (lane >> 4) * 8;
        bf16x8 a[2], b[2];
        #pragma unroll
        for (int mi = 0; mi < 2; ++mi) a[mi] = *(const bf16x8*)&As[wr * 32 + mi * 16 + fr][ko];
        #pragma unroll
        for (int ni = 0; ni < 2; ++ni) b[ni] = *(const bf16x8*)&Bs[wc * 32 + ni * 16 + fr][ko];
        #pragma unroll
        for (int mi = 0; mi < 2; ++mi)
            #pragma unroll
            for (int ni = 0; ni < 2; ++ni)
                acc[mi][ni] = __builtin_amdgcn_mfma_f32_16x16x32_bf16(a[mi], b[ni], acc[mi][ni], 0, 0, 0);
        __syncthreads();
    }

    const float g0 = gamma[0];
    const int fr = lane & 15;
    const int rg = (lane >> 4) * 4;
    #pragma unroll
    for (int mi = 0; mi < 2; ++mi) {
        #pragma unroll
        for (int r = 0; r < 4; ++r) {
            int gm = row0 + wr * 32 + mi * 16 + rg + r;
            if (gm < M) {
                #pragma unroll
                for (int ni = 0; ni < 2; ++ni) {
                    int gn = wc * 32 + ni * 16 + fr;
                    float v = acc[mi][ni][r] + b2[gn];
                    h[(size_t)gm * OUT_ + gn] = f2bf(v);
                    out[(size_t)gm * OUT_ + gn] = g0 * v;
                }
            }
        }
    }
}

// ---------------- propagation: CSR pull, bf16, 8 gathers in flight ----------------
// nt on ecsr/out/hn: reserve L2 for the random hc gathers (the only reused stream)
__global__ __launch_bounds__(256) void pull_kernel(const int* __restrict__ off,
                                                   const long long* __restrict__ ecsr,
                                                   const unsigned short* __restrict__ hc,
                                                   unsigned short* __restrict__ hn,
                                                   float* __restrict__ out,
                                                   const float* __restrict__ gamma,
                                                   int k, int n) {
    int node = blockIdx.x * 4 + (threadIdx.x >> 6);
    if (node >= n) return;
    int lane = threadIdx.x & 63;
    int half = lane >> 5;
    int fl = (lane & 31) * 2;
    int s = off[node], e = off[node + 1];
    float acc0 = 0.f, acc1 = 0.f;

    int j = s + half;
    // 8 edges per half per iteration -> 8 outstanding gathers per lane
    for (; j + 14 < e; j += 16) {
        long long p0 = __builtin_nontemporal_load(&ecsr[j]);
        long long p1 = __builtin_nontemporal_load(&ecsr[j + 2]);
        long long p2 = __builtin_nontemporal_load(&ecsr[j + 4]);
        long long p3 = __builtin_nontemporal_load(&ecsr[j + 6]);
        long long p4 = __builtin_nontemporal_load(&ecsr[j + 8]);
        long long p5 = __builtin_nontemporal_load(&ecsr[j + 10]);
        long long p6 = __builtin_nontemporal_load(&ecsr[j + 12]);
        long long p7 = __builtin_nontemporal_load(&ecsr[j + 14]);
        unsigned int v0 = *(const unsigned int*)&hc[(size_t)(unsigned int)p0 * OUT_ + fl];
        unsigned int v1 = *(const unsigned int*)&hc[(size_t)(unsigned int)p1 * OUT_ + fl];
        unsigned int v2 = *(const unsigned int*)&hc[(size_t)(unsigned int)p2 * OUT_ + fl];
        unsigned int v3 = *(const unsigned int*)&hc[(size_t)(unsigned int)p3 * OUT_ + fl];
        unsigned int v4 = *(const unsigned int*)&hc[(size_t)(unsigned int)p4 * OUT_ + fl];
        unsigned int v5 = *(const unsigned int*)&hc[(size_t)(unsigned int)p5 * OUT_ + fl];
        unsigned int v6 = *(const unsigned int*)&hc[(size_t)(unsigned int)p6 * OUT_ + fl];
        unsigned int v7 = *(const unsigned int*)&hc[(size_t)(unsigned int)p7 * OUT_ + fl];
        float w0 = __int_as_float((int)(p0 >> 32)), w1 = __int_as_float((int)(p1 >> 32));
        float w2 = __int_as_float((int)(p2 >> 32)), w3 = __int_as_float((int)(p3 >> 32));
        float w4 = __int_as_float((int)(p4 >> 32)), w5 = __int_as_float((int)(p5 >> 32));
        float w6 = __int_as_float((int)(p6 >> 32)), w7 = __int_as_float((int)(p7 >> 32));
        acc0 += w0 * bflo(v0); acc1 += w0 * bfhi(v0);
        acc0 += w1 * bflo(v1); acc1 += w1 * bfhi(v1);
        acc0 += w2 * bflo(v2); acc1 += w2 * bfhi(v2);
        acc0 += w3 * bflo(v3); acc1 += w3 * bfhi(v3);
        acc0 += w4 * bflo(v4); acc1 += w4 * bfhi(v4);
        acc0 += w5 * bflo(v5); acc1 += w5 * bfhi(v5);
        acc0 += w6 * bflo(v6); acc1 += w6 * bfhi(v6);
        acc0 += w7 * bflo(v7); acc1 += w7 * bfhi(v7);
    }
    for (; j + 2 < e; j += 4) {
        long long pa = __builtin_nontemporal_load(&ecsr[j]);
        long long pb = __builtin_nontemporal_load(&ecsr[j + 2]);
        unsigned int va = *(const unsigned int*)&hc[(size_t)(unsigned int)pa * OUT_ + fl];
        unsigned int vb = *(const unsigned int*)&hc[(size_t)(unsigned int)pb * OUT_ + fl];
        float wa = __int_as_float((int)(pa >> 32)), wb = __int_as_float((int)(pb >> 32));
        acc0 += wa * bflo(va); acc1 += wa * bfhi(va);
        acc0 += wb * bflo(vb); acc1 += wb * bfhi(vb);
    }
    if (j < e) {
        long long p = __builtin_nontemporal_load(&ecsr[j]);
        unsigned int v = *(const unsigned int*)&hc[(size_t)(unsigned int)p * OUT_ + fl];
        float w = __int_as_float((int)(p >> 32));
        acc0 += w * bflo(v);
        acc1 += w * bfhi(v);
    }

    acc0 += __shfl_xor(acc0, 32);
    acc1 += __shfl_xor(acc1, 32);

    if (lane < 32) {
        float g = gamma[k];
        size_t o = (size_t)node * OUT_ + fl;
        unsigned int packed = (unsigned int)f2bf(acc0) | ((unsigned int)f2bf(acc1) << 16);
        __builtin_nontemporal_store(packed, (unsigned int*)&hn[o]);
        float* op = &out[o];
        float ox = __builtin_nontemporal_load(op);
        float oy = __builtin_nontemporal_load(op + 1);
        __builtin_nontemporal_store(ox + g * acc0, op);
        __builtin_nontemporal_store(oy + g * acc1, op + 1);
    }
}

// ---------------- launcher ----------------
extern "C" void kernel_launch(void* const* d_in, const int* in_sizes, int n_in,
                              void* d_out, int out_size, void* d_ws, size_t ws_size,
                              hipStream_t stream) {
    const float* x = (const float*)d_in[0];
    const int* ei = (const int*)d_in[1];
    const float* W1 = (const float*)d_in[2];
    const float* b1 = (const float*)d_in[3];
    const float* W2 = (const float*)d_in[4];
    const float* b2 = (const float*)d_in[5];
    const float* alpha = (const float*)d_in[6];
    const int* row = ei;
    const int* col = ei + N_EDGES;
    float* out = (float*)d_out;

    const int NBLK = (N_NODES + 255) / 256;  // 391

    char* wsb = (char*)d_ws;
    size_t p = 0;
    auto alloc = [&](size_t bytes) { size_t r = p; p += (bytes + 255) & ~255ull; return r; };
    float* gamma = (float*)(wsb + alloc(16 * 4));
    int* off     = (int*)(wsb + alloc((N_NODES + 1) * 4));
    int* cursor  = (int*)(wsb + alloc(N_NODES * 4));
    int* deg     = (int*)(wsb + alloc(N_NODES * 4));
    float* dis   = (float*)(wsb + alloc(N_NODES * 4));
    int* bsum    = (int*)(wsb + alloc(512 * 4));
    unsigned short* w1T = (unsigned short*)(wsb + alloc((size_t)IN_DIM_ * HID_ * 2));  // [n][k]
    unsigned short* w2T = (unsigned short*)(wsb + alloc((size_t)HID_ * OUT_ * 2));     // [n][k]
    long long* ecsr = (long long*)(wsb + alloc((size_t)N_EDGES * 8));
    unsigned short* h1  = (unsigned short*)(wsb + alloc((size_t)N_NODES * HID_ * 2));  // 51.2MB
    unsigned short* h_a = (unsigned short*)(wsb + alloc((size_t)N_NODES * OUT_ * 2));  // 12.8MB
    unsigned short* h_b = h1;  // h1 dead after gemm2

    hipMemsetAsync(cursor, 0, N_NODES * sizeof(int), stream);
    hipMemsetAsync(deg, 0, N_NODES * sizeof(int), stream);
    gamma_kernel<<<1, 64, 0, stream>>>(alpha, gamma);
    deg_kernel<<<(N_EDGES + 255) / 256, 256, 0, stream>>>(row, deg, N_EDGES);
    dis_kernel<<<NBLK, 256, 0, stream>>>(deg, dis, N_NODES);
    scan_sum_kernel<<<NBLK, 256, 0, stream>>>(deg, bsum, N_NODES);
    scan_block_kernel<<<1, 512, 0, stream>>>(bsum, off, NBLK, N_NODES);
    scan_final_kernel<<<NBLK, 256, 0, stream>>>(deg, bsum, off, N_NODES);
    csr_scatter_kernel<<<(N_EDGES + 255) / 256, 256, 0, stream>>>(row, col, dis, off, cursor,
                                                                  ecsr, N_EDGES);
    wcast_kernel<<<dim3(1, HID_), 256, 0, stream>>>(W1, w1T, IN_DIM_, HID_);
    wcast_kernel<<<dim3(1, OUT_), 256, 0, stream>>>(W2, w2T, HID_, OUT_);

    gemm1_kernel<<<(N_NODES + 63) / 64, 256, 0, stream>>>(x, w1T, b1, h1, N_NODES);
    gemm2_kernel<<<(N_NODES + 63) / 64, 256, 0, stream>>>(h1, w2T, b2, gamma, h_a, out, N_NODES);

    unsigned short* hc = h_a;
    unsigned short* hn = h_b;
    for (int k = 1; k <= KSTEPS; ++k) {
        pull_kernel<<<(N_NODES + 3) / 4, 256, 0, stream>>>(off, ecsr, hc, hn, out, gamma, k,
                                                           N_NODES);
        unsigned short* t = hc; hc = hn; hn = t;
    }
}

// Round 8
// 987.951 us; speedup vs baseline: 1.0206x; 1.0206x over previous
//
#include <hip/hip_runtime.h>
#include <hip/hip_bf16.h>

#define N_NODES 100000
#define N_EDGES 1600000
#define IN_DIM_ 256
#define HID_ 256
#define OUT_ 64
#define KSTEPS 10

typedef __attribute__((ext_vector_type(4))) float f32x4;
typedef __attribute__((ext_vector_type(8))) __bf16 bf16x8;
typedef __attribute__((ext_vector_type(8))) unsigned short u16x8;

static __device__ __forceinline__ unsigned short f2bf(float f) {
    union { float f; unsigned int u; } v; v.f = f;
    unsigned int u = v.u;
    unsigned int r = u + 0x7FFFu + ((u >> 16) & 1u);  // RNE
    return (unsigned short)(r >> 16);
}
static __device__ __forceinline__ float bflo(unsigned int v) {
    return __uint_as_float(v << 16);
}
static __device__ __forceinline__ float bfhi(unsigned int v) {
    return __uint_as_float(v & 0xFFFF0000u);
}

// ---------------- small setup kernels ----------------

__global__ void gamma_kernel(const float* __restrict__ alpha, float* __restrict__ gamma) {
    if (threadIdx.x == 0) {
        float m = alpha[0];
        for (int i = 1; i <= KSTEPS; ++i) m = fmaxf(m, alpha[i]);
        float e[KSTEPS + 1];
        float s = 0.f;
        for (int i = 0; i <= KSTEPS; ++i) { e[i] = expf(alpha[i] - m); s += e[i]; }
        float inv = 1.f / s;
        for (int i = 0; i <= KSTEPS; ++i) gamma[i] = e[i] * inv;
    }
}

__global__ void deg_kernel(const int* __restrict__ row, int* __restrict__ deg, int E) {
    int e = blockIdx.x * 256 + threadIdx.x;
    if (e < E) atomicAdd(&deg[row[e]], 1);
}

__global__ void dis_kernel(const int* __restrict__ deg, float* __restrict__ dis, int n) {
    int i = blockIdx.x * 256 + threadIdx.x;
    if (i < n) {
        int d = deg[i];
        dis[i] = d > 0 ? rsqrtf((float)d) : 0.f;
    }
}

// transpose+cast weights once: wT[n][k] = bf16(W[k][n])
__global__ void wcast_kernel(const float* __restrict__ W, unsigned short* __restrict__ wT,
                             int K, int N) {
    int k = blockIdx.x * 256 + threadIdx.x;
    int n = blockIdx.y;
    if (k < K) wT[(size_t)n * K + k] = f2bf(W[(size_t)k * N + n]);
}

// ---------------- hierarchical scan ----------------

__global__ __launch_bounds__(256) void scan_sum_kernel(const int* __restrict__ deg,
                                                       int* __restrict__ bsum, int n) {
    __shared__ int s[256];
    int t = threadIdx.x;
    int i = blockIdx.x * 256 + t;
    s[t] = (i < n) ? deg[i] : 0;
    __syncthreads();
    for (int st = 128; st > 0; st >>= 1) {
        if (t < st) s[t] += s[t + st];
        __syncthreads();
    }
    if (t == 0) bsum[blockIdx.x] = s[0];
}

__global__ __launch_bounds__(512) void scan_block_kernel(int* __restrict__ bsum,
                                                         int* __restrict__ off,
                                                         int nblk, int n) {
    __shared__ int s[512];
    int t = threadIdx.x;
    int v = (t < nblk) ? bsum[t] : 0;
    s[t] = v;
    __syncthreads();
    for (int st = 1; st < 512; st <<= 1) {
        int a = (t >= st) ? s[t - st] : 0;
        __syncthreads();
        s[t] += a;
        __syncthreads();
    }
    if (t < nblk) bsum[t] = s[t] - v;  // exclusive
    if (t == 511) off[n] = s[511];     // total = E
}

__global__ __launch_bounds__(256) void scan_final_kernel(const int* __restrict__ deg,
                                                         const int* __restrict__ bsum,
                                                         int* __restrict__ off, int n) {
    __shared__ int s[256];
    int t = threadIdx.x;
    int i = blockIdx.x * 256 + t;
    int v = (i < n) ? deg[i] : 0;
    s[t] = v;
    __syncthreads();
    for (int st = 1; st < 256; st <<= 1) {
        int a = (t >= st) ? s[t - st] : 0;
        __syncthreads();
        s[t] += a;
        __syncthreads();
    }
    if (i < n) off[i] = bsum[blockIdx.x] + s[t] - v;
}

// ---------------- bucketed CSR build (R8) ----------------
// R6/R7 counters: direct per-node scatter had 8x write amplification (101 MB HBM
// writes for 12.8 MB payload: temporally-random 8B stores dirty whole 64B lines).
// Pass A: bucket by row>>6. Within-bucket writes are sequential-in-time via the
// bucket cursor -> lines fill before eviction. Payload 8B: {(row&63)<<26|col, w}.
__global__ void bucket_scatter_kernel(const int* __restrict__ row, const int* __restrict__ col,
                                      const float* __restrict__ dis, const int* __restrict__ off,
                                      int* __restrict__ bcur, int2* __restrict__ ebuf, int E) {
    int e = blockIdx.x * 256 + threadIdx.x;
    if (e < E) {
        int r = row[e], c = col[e];
        float w = dis[r] * dis[c];
        int b = r >> 6;
        int pos = atomicAdd(&bcur[b], 1);
        int base = off[b << 6];  // bucket start: edges of nodes [b*64, b*64+64)
        int2 p;
        p.x = ((r & 63) << 26) | c;  // col < 2^17, delta 6 bits
        p.y = __float_as_int(w);
        ebuf[(size_t)base + pos] = p;
    }
}

// Pass B: one block per bucket; per-node LDS cursors; final {col,w} writes land
// inside the bucket's ~8KB window (L2-hot) -> no line amplification.
__global__ __launch_bounds__(256) void bucket_place_kernel(const int* __restrict__ off,
                                                           const int2* __restrict__ ebuf,
                                                           int2* __restrict__ ecsr, int n) {
    __shared__ int cur[64];
    int b = blockIdx.x;
    int n0 = b << 6;
    int nend = min(n0 + 64, n);
    int t = threadIdx.x;
    if (t < nend - n0) cur[t] = off[n0 + t];
    __syncthreads();
    int lo = off[n0], hi = off[nend];
    for (int i = lo + t; i < hi; i += 256) {
        int2 p = ebuf[i];
        int dlt = (unsigned int)p.x >> 26;
        int c = p.x & 0x3FFFFFF;
        int pos = atomicAdd(&cur[dlt], 1);
        int2 q;
        q.x = c;
        q.y = p.y;
        ecsr[pos] = q;
    }
}

// ---------------- MLP ----------------
// GEMM1 single-pass: block computes 64 rows x 256 cols. x fetched exactly once.
__global__ __launch_bounds__(256) void gemm1_kernel(const float* __restrict__ x,
                                                    const unsigned short* __restrict__ w1T,
                                                    const float* __restrict__ b1,
                                                    unsigned short* __restrict__ h1, int M) {
    __shared__ unsigned short As[64][40];
    __shared__ unsigned short Bs[256][40];

    const int tid = threadIdx.x;
    const int lane = tid & 63;
    const int w = tid >> 6;
    const int wr = w >> 1, wc = w & 1;          // wave tile: rows wr*32, cols wc*128
    const int row0 = blockIdx.x * 64;

    const int am = tid >> 2;
    const int ak = (tid & 3) * 8;

    f32x4 acc[2][8] = {};

    for (int kk = 0; kk < 256; kk += 32) {
        {
            int gr = row0 + am;
            u16x8 av;
            if (gr < M) {
                const float* p = x + (size_t)gr * IN_DIM_ + kk + ak;
                #pragma unroll
                for (int j = 0; j < 8; ++j) av[j] = f2bf(p[j]);
            } else {
                #pragma unroll
                for (int j = 0; j < 8; ++j) av[j] = 0;
            }
            *(u16x8*)&As[am][ak] = av;
        }
        {
            const unsigned short* p = w1T + (size_t)tid * 256 + kk;
            *(u16x8*)&Bs[tid][0]  = *(const u16x8*)&p[0];
            *(u16x8*)&Bs[tid][8]  = *(const u16x8*)&p[8];
            *(u16x8*)&Bs[tid][16] = *(const u16x8*)&p[16];
            *(u16x8*)&Bs[tid][24] = *(const u16x8*)&p[24];
        }
        __syncthreads();

        const int fr = lane & 15;
        const int ko = (lane >> 4) * 8;
        bf16x8 a[2];
        #pragma unroll
        for (int mi = 0; mi < 2; ++mi) a[mi] = *(const bf16x8*)&As[wr * 32 + mi * 16 + fr][ko];
        #pragma unroll
        for (int ni = 0; ni < 8; ++ni) {
            bf16x8 b = *(const bf16x8*)&Bs[wc * 128 + ni * 16 + fr][ko];
            #pragma unroll
            for (int mi = 0; mi < 2; ++mi)
                acc[mi][ni] = __builtin_amdgcn_mfma_f32_16x16x32_bf16(a[mi], b, acc[mi][ni], 0, 0, 0);
        }
        __syncthreads();
    }

    const int fr = lane & 15;
    const int rg = (lane >> 4) * 4;
    #pragma unroll
    for (int mi = 0; mi < 2; ++mi) {
        #pragma unroll
        for (int r = 0; r < 4; ++r) {
            int gm = row0 + wr * 32 + mi * 16 + rg + r;
            if (gm < M) {
                #pragma unroll
                for (int ni = 0; ni < 8; ++ni) {
                    int gn = wc * 128 + ni * 16 + fr;
                    float v = acc[mi][ni][r] + b1[gn];
                    v = fmaxf(v, 0.f);
                    h1[(size_t)gm * HID_ + gn] = f2bf(v);
                }
            }
        }
    }
}

// GEMM2: h = h1 @ W2 + b2 -> h bf16 [M,64]; out = gamma0*h (f32 pre-rounding)
__global__ __launch_bounds__(256) void gemm2_kernel(const unsigned short* __restrict__ h1,
                                                    const unsigned short* __restrict__ w2T,
                                                    const float* __restrict__ b2,
                                                    const float* __restrict__ gamma,
                                                    unsigned short* __restrict__ h,
                                                    float* __restrict__ out, int M) {
    __shared__ unsigned short As[64][40];
    __shared__ unsigned short Bs[64][40];

    const int tid = threadIdx.x;
    const int lane = tid & 63;
    const int w = tid >> 6;
    const int wr = w >> 1, wc = w & 1;
    const int row0 = blockIdx.x * 64;

    const int am = tid >> 2;
    const int ak = (tid & 3) * 8;

    f32x4 acc[2][2] = {};

    for (int kk = 0; kk < 256; kk += 32) {
        {
            int gr = row0 + am;
            if (gr < M) {
                *(u16x8*)&As[am][ak] = *(const u16x8*)&h1[(size_t)gr * HID_ + kk + ak];
            } else {
                u16x8 z = {};
                *(u16x8*)&As[am][ak] = z;
            }
        }
        if (tid < 128) {
            int n = tid >> 1, hf = (tid & 1) * 16;
            const unsigned short* p = &w2T[(size_t)n * 256 + kk + hf];
            *(u16x8*)&Bs[n][hf]     = *(const u16x8*)&p[0];
            *(u16x8*)&Bs[n][hf + 8] = *(const u16x8*)&p[8];
        }
        __syncthreads();

        const int fr = lane & 15;
        const int ko = (lane >> 4) * 8;
        bf16x8 a[2], b[2];
        #pragma unroll
        for (int mi = 0; mi < 2; ++mi) a[mi] = *(const bf16x8*)&As[wr * 32 + mi * 16 + fr][ko];
        #pragma unroll
        for (int ni = 0; ni < 2; ++ni) b[ni] = *(const bf16x8*)&Bs[wc * 32 + ni * 16 + fr][ko];
        #pragma unroll
        for (int mi = 0; mi < 2; ++mi)
            #pragma unroll
            for (int ni = 0; ni < 2; ++ni)
                acc[mi][ni] = __builtin_amdgcn_mfma_f32_16x16x32_bf16(a[mi], b[ni], acc[mi][ni], 0, 0, 0);
        __syncthreads();
    }

    const float g0 = gamma[0];
    const int fr = lane & 15;
    const int rg = (lane >> 4) * 4;
    #pragma unroll
    for (int mi = 0; mi < 2; ++mi) {
        #pragma unroll
        for (int r = 0; r < 4; ++r) {
            int gm = row0 + wr * 32 + mi * 16 + rg + r;
            if (gm < M) {
                #pragma unroll
                for (int ni = 0; ni < 2; ++ni) {
                    int gn = wc * 32 + ni * 16 + fr;
                    float v = acc[mi][ni][r] + b2[gn];
                    h[(size_t)gm * OUT_ + gn] = f2bf(v);
                    out[(size_t)gm * OUT_ + gn] = g0 * v;
                }
            }
        }
    }
}

// ---------------- propagation: CSR pull, bf16, 8 gathers in flight (R6 form) ----------------
__global__ __launch_bounds__(256) void pull_kernel(const int* __restrict__ off,
                                                   const int2* __restrict__ ecsr,
                                                   const unsigned short* __restrict__ hc,
                                                   unsigned short* __restrict__ hn,
                                                   float* __restrict__ out,
                                                   const float* __restrict__ gamma,
                                                   int k, int n) {
    int node = blockIdx.x * 4 + (threadIdx.x >> 6);
    if (node >= n) return;
    int lane = threadIdx.x & 63;
    int half = lane >> 5;
    int fl = (lane & 31) * 2;
    int s = off[node], e = off[node + 1];
    float acc0 = 0.f, acc1 = 0.f;

    int j = s + half;
    // 8 edges per half per iteration -> 8 outstanding gathers per lane
    for (; j + 14 < e; j += 16) {
        int2 p0 = ecsr[j],      p1 = ecsr[j + 2],  p2 = ecsr[j + 4],  p3 = ecsr[j + 6];
        int2 p4 = ecsr[j + 8],  p5 = ecsr[j + 10], p6 = ecsr[j + 12], p7 = ecsr[j + 14];
        unsigned int v0 = *(const unsigned int*)&hc[(size_t)p0.x * OUT_ + fl];
        unsigned int v1 = *(const unsigned int*)&hc[(size_t)p1.x * OUT_ + fl];
        unsigned int v2 = *(const unsigned int*)&hc[(size_t)p2.x * OUT_ + fl];
        unsigned int v3 = *(const unsigned int*)&hc[(size_t)p3.x * OUT_ + fl];
        unsigned int v4 = *(const unsigned int*)&hc[(size_t)p4.x * OUT_ + fl];
        unsigned int v5 = *(const unsigned int*)&hc[(size_t)p5.x * OUT_ + fl];
        unsigned int v6 = *(const unsigned int*)&hc[(size_t)p6.x * OUT_ + fl];
        unsigned int v7 = *(const unsigned int*)&hc[(size_t)p7.x * OUT_ + fl];
        float w0 = __int_as_float(p0.y), w1 = __int_as_float(p1.y);
        float w2 = __int_as_float(p2.y), w3 = __int_as_float(p3.y);
        float w4 = __int_as_float(p4.y), w5 = __int_as_float(p5.y);
        float w6 = __int_as_float(p6.y), w7 = __int_as_float(p7.y);
        acc0 += w0 * bflo(v0); acc1 += w0 * bfhi(v0);
        acc0 += w1 * bflo(v1); acc1 += w1 * bfhi(v1);
        acc0 += w2 * bflo(v2); acc1 += w2 * bfhi(v2);
        acc0 += w3 * bflo(v3); acc1 += w3 * bfhi(v3);
        acc0 += w4 * bflo(v4); acc1 += w4 * bfhi(v4);
        acc0 += w5 * bflo(v5); acc1 += w5 * bfhi(v5);
        acc0 += w6 * bflo(v6); acc1 += w6 * bfhi(v6);
        acc0 += w7 * bflo(v7); acc1 += w7 * bfhi(v7);
    }
    for (; j + 2 < e; j += 4) {
        int2 pa = ecsr[j], pb = ecsr[j + 2];
        unsigned int va = *(const unsigned int*)&hc[(size_t)pa.x * OUT_ + fl];
        unsigned int vb = *(const unsigned int*)&hc[(size_t)pb.x * OUT_ + fl];
        float wa = __int_as_float(pa.y), wb = __int_as_float(pb.y);
        acc0 += wa * bflo(va); acc1 += wa * bfhi(va);
        acc0 += wb * bflo(vb); acc1 += wb * bfhi(vb);
    }
    if (j < e) {
        int2 p = ecsr[j];
        unsigned int v = *(const unsigned int*)&hc[(size_t)p.x * OUT_ + fl];
        float w = __int_as_float(p.y);
        acc0 += w * bflo(v);
        acc1 += w * bfhi(v);
    }

    acc0 += __shfl_xor(acc0, 32);
    acc1 += __shfl_xor(acc1, 32);

    if (lane < 32) {
        float g = gamma[k];
        size_t o = (size_t)node * OUT_ + fl;
        unsigned int packed = (unsigned int)f2bf(acc0) | ((unsigned int)f2bf(acc1) << 16);
        *(unsigned int*)&hn[o] = packed;
        float2* op = (float2*)&out[o];
        float2 ov = *op;
        ov.x += g * acc0;
        ov.y += g * acc1;
        *op = ov;
    }
}

// ---------------- launcher ----------------
extern "C" void kernel_launch(void* const* d_in, const int* in_sizes, int n_in,
                              void* d_out, int out_size, void* d_ws, size_t ws_size,
                              hipStream_t stream) {
    const float* x = (const float*)d_in[0];
    const int* ei = (const int*)d_in[1];
    const float* W1 = (const float*)d_in[2];
    const float* b1 = (const float*)d_in[3];
    const float* W2 = (const float*)d_in[4];
    const float* b2 = (const float*)d_in[5];
    const float* alpha = (const float*)d_in[6];
    const int* row = ei;
    const int* col = ei + N_EDGES;
    float* out = (float*)d_out;

    const int NBLK = (N_NODES + 255) / 256;   // 391
    const int NBKT = (N_NODES + 63) / 64;     // 1563

    char* wsb = (char*)d_ws;
    size_t p = 0;
    auto alloc = [&](size_t bytes) { size_t r = p; p += (bytes + 255) & ~255ull; return r; };
    float* gamma = (float*)(wsb + alloc(16 * 4));
    int* off     = (int*)(wsb + alloc((N_NODES + 1) * 4));
    int* bcur    = (int*)(wsb + alloc(NBKT * 4));
    int* deg     = (int*)(wsb + alloc(N_NODES * 4));
    float* dis   = (float*)(wsb + alloc(N_NODES * 4));
    int* bsum    = (int*)(wsb + alloc(512 * 4));
    unsigned short* w1T = (unsigned short*)(wsb + alloc((size_t)IN_DIM_ * HID_ * 2));  // [n][k]
    unsigned short* w2T = (unsigned short*)(wsb + alloc((size_t)HID_ * OUT_ * 2));     // [n][k]
    int2* ebuf   = (int2*)(wsb + alloc((size_t)N_EDGES * 8));  // bucketed staging
    int2* ecsr   = (int2*)(wsb + alloc((size_t)N_EDGES * 8));
    unsigned short* h1  = (unsigned short*)(wsb + alloc((size_t)N_NODES * HID_ * 2));  // 51.2MB
    unsigned short* h_a = (unsigned short*)(wsb + alloc((size_t)N_NODES * OUT_ * 2));  // 12.8MB
    unsigned short* h_b = h1;  // h1 dead after gemm2

    hipMemsetAsync(bcur, 0, NBKT * sizeof(int), stream);
    hipMemsetAsync(deg, 0, N_NODES * sizeof(int), stream);
    gamma_kernel<<<1, 64, 0, stream>>>(alpha, gamma);
    deg_kernel<<<(N_EDGES + 255) / 256, 256, 0, stream>>>(row, deg, N_EDGES);
    dis_kernel<<<NBLK, 256, 0, stream>>>(deg, dis, N_NODES);
    scan_sum_kernel<<<NBLK, 256, 0, stream>>>(deg, bsum, N_NODES);
    scan_block_kernel<<<1, 512, 0, stream>>>(bsum, off, NBLK, N_NODES);
    scan_final_kernel<<<NBLK, 256, 0, stream>>>(deg, bsum, off, N_NODES);
    bucket_scatter_kernel<<<(N_EDGES + 255) / 256, 256, 0, stream>>>(row, col, dis, off, bcur,
                                                                     ebuf, N_EDGES);
    bucket_place_kernel<<<NBKT, 256, 0, stream>>>(off, ebuf, ecsr, N_NODES);
    wcast_kernel<<<dim3(1, HID_), 256, 0, stream>>>(W1, w1T, IN_DIM_, HID_);
    wcast_kernel<<<dim3(1, OUT_), 256, 0, stream>>>(W2, w2T, HID_, OUT_);

    gemm1_kernel<<<(N_NODES + 63) / 64, 256, 0, stream>>>(x, w1T, b1, h1, N_NODES);
    gemm2_kernel<<<(N_NODES + 63) / 64, 256, 0, stream>>>(h1, w2T, b2, gamma, h_a, out, N_NODES);

    unsigned short* hc = h_a;
    unsigned short* hn = h_b;
    for (int k = 1; k <= KSTEPS; ++k) {
        pull_kernel<<<(N_NODES + 3) / 4, 256, 0, stream>>>(off, ecsr, hc, hn, out, gamma, k,
                                                           N_NODES);
        unsigned short* t = hc; hc = hn; hn = t;
    }
}